// Round 2
// baseline (967.300 us; speedup 1.0000x reference)
//
#include <hip/hip_runtime.h>

// Problem constants (match reference setup_inputs / CUTOFF / N_IMAGES)
constexpr int M = 8;
constexpr int N = 400;
constexpr int K = 27;               // (2*N_IMAGES+1)^3
constexpr float CUT2 = 36.0f;       // CUTOFF^2
constexpr int D  = M * K * N * N;   // 34,560,000 elements per [M,K,N,N] output
constexpr int F4 = D / 4;           // 8,640,000 float4 units per such region

typedef float f32x4 __attribute__((ext_vector_type(4)));

// ws layout (floats/ints):
//   wrapped : float[M*N*3]  at byte 0        (38400 B)
//   wo      : int  [M*N*3]  at byte 38400    (38400 B)
//   shift   : float[M*K*3]  at byte 76800    ( 2592 B)
constexpr int WS_WRAPPED = 0;
constexpr int WS_WO      = 38400;
constexpr int WS_SHIFT   = 76800;

__global__ __launch_bounds__(128)
void setup_kernel(const float* __restrict__ coords, const float* __restrict__ cell,
                  float* __restrict__ wrapped, int* __restrict__ wo,
                  float* __restrict__ shift)
{
    int m = blockIdx.x;
    const float* c = cell + m * 9;
    float c00 = c[0], c01 = c[1], c02 = c[2];
    float c10 = c[3], c11 = c[4], c12 = c[5];
    float c20 = c[6], c21 = c[7], c22 = c[8];

    // 3x3 inverse via adjugate (cell is well-conditioned here)
    float det = c00 * (c11 * c22 - c12 * c21)
              - c01 * (c10 * c22 - c12 * c20)
              + c02 * (c10 * c21 - c11 * c20);
    float rd = 1.0f / det;
    float i00 = (c11 * c22 - c12 * c21) * rd, i01 = (c02 * c21 - c01 * c22) * rd, i02 = (c01 * c12 - c02 * c11) * rd;
    float i10 = (c12 * c20 - c10 * c22) * rd, i11 = (c00 * c22 - c02 * c20) * rd, i12 = (c02 * c10 - c00 * c12) * rd;
    float i20 = (c10 * c21 - c11 * c20) * rd, i21 = (c01 * c20 - c00 * c21) * rd, i22 = (c00 * c11 - c01 * c10) * rd;

    for (int n = threadIdx.x; n < N; n += blockDim.x) {
        int b = (m * N + n) * 3;
        float x = coords[b + 0], y = coords[b + 1], z = coords[b + 2];
        // proj[e] = sum_d coord[d] * inv[d][e]
        float p0 = x * i00 + y * i10 + z * i20;
        float p1 = x * i01 + y * i11 + z * i21;
        float p2 = x * i02 + y * i12 + z * i22;
        float f0 = floorf(p0), f1 = floorf(p1), f2 = floorf(p2);
        // wrapped[d] = coord[d] - sum_e off[e] * cell[e][d]
        wrapped[b + 0] = x - (f0 * c00 + f1 * c10 + f2 * c20);
        wrapped[b + 1] = y - (f0 * c01 + f1 * c11 + f2 * c21);
        wrapped[b + 2] = z - (f0 * c02 + f1 * c12 + f2 * c22);
        wo[b + 0] = (int)f0;
        wo[b + 1] = (int)f1;
        wo[b + 2] = (int)f2;
    }

    if (threadIdx.x < K) {
        int k = threadIdx.x;
        float fx = (float)(k / 9 - 1);
        float fy = (float)((k / 3) % 3 - 1);
        float fz = (float)(k % 3 - 1);
        int sb = (m * K + k) * 3;
        // shift[d] = sum_c image[c] * cell[c][d]
        shift[sb + 0] = fx * c00 + fy * c10 + fz * c20;
        shift[sb + 1] = fx * c01 + fy * c11 + fz * c21;
        shift[sb + 2] = fx * c02 + fy * c12 + fz * c22;
    }
}

__global__ __launch_bounds__(256)
void pairs_kernel(const float* __restrict__ wrapped, const int* __restrict__ wo,
                  const float* __restrict__ shift, float* __restrict__ out)
{
    int t = blockIdx.x * 256 + threadIdx.x;   // [0, M*K*N*(N/4)) = [0, 8,640,000)
    int jq = t % (N / 4);                     // j-quad within row
    int r  = t / (N / 4);                     // row = (m*K + k)*N + i
    int i  = r % N;
    int mk = r / N;
    int k  = mk % K;
    int m  = mk / K;
    int j0 = 4 * jq;

    // 4 consecutive j atoms: 12 floats = 3 aligned float4 loads
    const float4* w4 = reinterpret_cast<const float4*>(wrapped + m * (N * 3)) + 3 * jq;
    float4 wa = w4[0], wb = w4[1], wc = w4[2];
    float wjx[4] = { wa.x, wa.w, wb.z, wc.y };
    float wjy[4] = { wa.y, wb.x, wb.w, wc.z };
    float wjz[4] = { wa.z, wb.y, wc.x, wc.w };

    const int4* o4j = reinterpret_cast<const int4*>(wo + m * (N * 3)) + 3 * jq;
    int4 oa = o4j[0], ob = o4j[1], oc = o4j[2];
    int ojx[4] = { oa.x, oa.w, ob.z, oc.y };
    int ojy[4] = { oa.y, ob.x, ob.w, oc.z };
    int ojz[4] = { oa.z, ob.y, oc.x, oc.w };

    int ib = m * (N * 3) + 3 * i;
    float wix = wrapped[ib], wiy = wrapped[ib + 1], wiz = wrapped[ib + 2];
    int   oix = wo[ib],      oiy = wo[ib + 1],      oiz = wo[ib + 2];
    float sx = shift[mk * 3], sy = shift[mk * 3 + 1], sz = shift[mk * 3 + 2];
    int imx = k / 9 - 1, imy = (k / 3) % 3 - 1, imz = k % 3 - 1;

    float dist[4], msk[4], offv[4], pc[12];
    #pragma unroll
    for (int dj = 0; dj < 4; ++dj) {
        // p = (wi - wj) + s, d2 = px*px + py*py + pz*pz  -- no FMA contraction,
        // matches numpy reference association for exact mask agreement at d2==36 boundary
        float px = __fadd_rn(__fsub_rn(wix, wjx[dj]), sx);
        float py = __fadd_rn(__fsub_rn(wiy, wjy[dj]), sy);
        float pz = __fadd_rn(__fsub_rn(wiz, wjz[dj]), sz);
        float d2 = __fadd_rn(__fadd_rn(__fmul_rn(px, px), __fmul_rn(py, py)),
                             __fmul_rn(pz, pz));
        bool mb = (d2 < CUT2) && !((k == (K / 2)) && (i == j0 + dj));
        dist[dj] = mb ? sqrtf(d2) : 0.0f;
        msk[dj]  = mb ? 1.0f : 0.0f;
        pc[3 * dj + 0] = mb ? px : 0.0f;
        pc[3 * dj + 1] = mb ? py : 0.0f;
        pc[3 * dj + 2] = mb ? pz : 0.0f;
        int ox = imx - (oix - ojx[dj]) + 1;
        int oy = imy - (oiy - ojy[dj]) + 1;
        int oz = imz - (oiz - ojz[dj]) + 1;
        offv[dj] = (float)(oz + 3 * (oy + 3 * ox));
    }

    f32x4* out4 = reinterpret_cast<f32x4*>(out);
    f32x4 dv = { dist[0], dist[1], dist[2], dist[3] };
    f32x4 mv = { msk[0],  msk[1],  msk[2],  msk[3]  };
    f32x4 ov = { offv[0], offv[1], offv[2], offv[3] };
    f32x4 p0 = { pc[0], pc[1], pc[2],  pc[3]  };
    f32x4 p1 = { pc[4], pc[5], pc[6],  pc[7]  };
    f32x4 p2 = { pc[8], pc[9], pc[10], pc[11] };

    // region layout in float4 units: dist [0,F4), paircoord [F4,4*F4),
    // mask [4*F4,5*F4), offset_index [5*F4,6*F4)
    __builtin_nontemporal_store(dv, out4 + t);
    __builtin_nontemporal_store(p0, out4 + F4 + 3 * t + 0);
    __builtin_nontemporal_store(p1, out4 + F4 + 3 * t + 1);
    __builtin_nontemporal_store(p2, out4 + F4 + 3 * t + 2);
    __builtin_nontemporal_store(mv, out4 + 4 * F4 + t);
    __builtin_nontemporal_store(ov, out4 + 5 * F4 + t);
}

extern "C" void kernel_launch(void* const* d_in, const int* in_sizes, int n_in,
                              void* d_out, int out_size, void* d_ws, size_t ws_size,
                              hipStream_t stream) {
    const float* coords = (const float*)d_in[0];   // [M,N,3]
    const float* cell   = (const float*)d_in[1];   // [M,3,3]
    float* out = (float*)d_out;

    char* ws = (char*)d_ws;
    float* wrapped = (float*)(ws + WS_WRAPPED);
    int*   wo      = (int*)  (ws + WS_WO);
    float* shift   = (float*)(ws + WS_SHIFT);

    setup_kernel<<<M, 128, 0, stream>>>(coords, cell, wrapped, wo, shift);

    int total = M * K * N * (N / 4);           // 8,640,000 threads
    int blocks = total / 256;                  // 33,750 exactly
    pairs_kernel<<<blocks, 256, 0, stream>>>(wrapped, wo, shift, out);
}

// Round 3
// 793.791 us; speedup vs baseline: 1.2186x; 1.2186x over previous
//
#include <hip/hip_runtime.h>

// Problem constants (match reference setup_inputs / CUTOFF / N_IMAGES)
constexpr int M = 8;
constexpr int N = 400;
constexpr int K = 27;               // (2*N_IMAGES+1)^3
constexpr float CUT2 = 36.0f;       // CUTOFF^2
constexpr int D  = M * K * N * N;   // 34,560,000 elements per [M,K,N,N] output
constexpr int F4 = D / 4;           // 8,640,000 float4 units per such region

typedef float f32x4 __attribute__((ext_vector_type(4)));

// ws layout (floats/ints):
//   wrapped : float[M*N*3]  at byte 0        (38400 B)
//   wo      : int  [M*N*3]  at byte 38400    (38400 B)
//   shift   : float[M*K*3]  at byte 76800    ( 2592 B)
constexpr int WS_WRAPPED = 0;
constexpr int WS_WO      = 38400;
constexpr int WS_SHIFT   = 76800;

__global__ __launch_bounds__(128)
void setup_kernel(const float* __restrict__ coords, const float* __restrict__ cell,
                  float* __restrict__ wrapped, int* __restrict__ wo,
                  float* __restrict__ shift)
{
    int m = blockIdx.x;
    const float* c = cell + m * 9;
    float c00 = c[0], c01 = c[1], c02 = c[2];
    float c10 = c[3], c11 = c[4], c12 = c[5];
    float c20 = c[6], c21 = c[7], c22 = c[8];

    // 3x3 inverse via adjugate (cell is well-conditioned here)
    float det = c00 * (c11 * c22 - c12 * c21)
              - c01 * (c10 * c22 - c12 * c20)
              + c02 * (c10 * c21 - c11 * c20);
    float rd = 1.0f / det;
    float i00 = (c11 * c22 - c12 * c21) * rd, i01 = (c02 * c21 - c01 * c22) * rd, i02 = (c01 * c12 - c02 * c11) * rd;
    float i10 = (c12 * c20 - c10 * c22) * rd, i11 = (c00 * c22 - c02 * c20) * rd, i12 = (c02 * c10 - c00 * c12) * rd;
    float i20 = (c10 * c21 - c11 * c20) * rd, i21 = (c01 * c20 - c00 * c21) * rd, i22 = (c00 * c11 - c01 * c10) * rd;

    for (int n = threadIdx.x; n < N; n += blockDim.x) {
        int b = (m * N + n) * 3;
        float x = coords[b + 0], y = coords[b + 1], z = coords[b + 2];
        float p0 = x * i00 + y * i10 + z * i20;
        float p1 = x * i01 + y * i11 + z * i21;
        float p2 = x * i02 + y * i12 + z * i22;
        float f0 = floorf(p0), f1 = floorf(p1), f2 = floorf(p2);
        wrapped[b + 0] = x - (f0 * c00 + f1 * c10 + f2 * c20);
        wrapped[b + 1] = y - (f0 * c01 + f1 * c11 + f2 * c21);
        wrapped[b + 2] = z - (f0 * c02 + f1 * c12 + f2 * c22);
        wo[b + 0] = (int)f0;
        wo[b + 1] = (int)f1;
        wo[b + 2] = (int)f2;
    }

    if (threadIdx.x < K) {
        int k = threadIdx.x;
        float fx = (float)(k / 9 - 1);
        float fy = (float)((k / 3) % 3 - 1);
        float fz = (float)(k % 3 - 1);
        int sb = (m * K + k) * 3;
        shift[sb + 0] = fx * c00 + fy * c10 + fz * c20;
        shift[sb + 1] = fx * c01 + fy * c11 + fz * c21;
        shift[sb + 2] = fx * c02 + fy * c12 + fz * c22;
    }
}

__global__ __launch_bounds__(256)
void pairs_kernel(const float* __restrict__ wrapped, const int* __restrict__ wo,
                  const float* __restrict__ shift, float* __restrict__ out)
{
    // LDS transpose buffer for paircoord: padded to 257 so write phase
    // (lane-stride 16B within each q-plane) and read phase (q*257 rotates
    // the bank base by 4 per plane) are conflict-free.
    __shared__ f32x4 lds[3][257];

    int tid = threadIdx.x;
    int t = blockIdx.x * 256 + tid;           // [0, M*K*N*(N/4)) = [0, 8,640,000)
    int jq = t % (N / 4);                     // j-quad within row
    int r  = t / (N / 4);                     // row = (m*K + k)*N + i
    int i  = r % N;
    int mk = r / N;
    int k  = mk % K;
    int m  = mk / K;
    int j0 = 4 * jq;

    // 4 consecutive j atoms: 12 floats = 3 aligned float4 loads
    const float4* w4 = reinterpret_cast<const float4*>(wrapped + m * (N * 3)) + 3 * jq;
    float4 wa = w4[0], wb = w4[1], wc = w4[2];
    float wjx[4] = { wa.x, wa.w, wb.z, wc.y };
    float wjy[4] = { wa.y, wb.x, wb.w, wc.z };
    float wjz[4] = { wa.z, wb.y, wc.x, wc.w };

    const int4* o4j = reinterpret_cast<const int4*>(wo + m * (N * 3)) + 3 * jq;
    int4 oa = o4j[0], ob = o4j[1], oc = o4j[2];
    int ojx[4] = { oa.x, oa.w, ob.z, oc.y };
    int ojy[4] = { oa.y, ob.x, ob.w, oc.z };
    int ojz[4] = { oa.z, ob.y, oc.x, oc.w };

    int ib = m * (N * 3) + 3 * i;
    float wix = wrapped[ib], wiy = wrapped[ib + 1], wiz = wrapped[ib + 2];
    int   oix = wo[ib],      oiy = wo[ib + 1],      oiz = wo[ib + 2];
    float sx = shift[mk * 3], sy = shift[mk * 3 + 1], sz = shift[mk * 3 + 2];
    int imx = k / 9 - 1, imy = (k / 3) % 3 - 1, imz = k % 3 - 1;

    float dist[4], msk[4], offv[4], pc[12];
    #pragma unroll
    for (int dj = 0; dj < 4; ++dj) {
        // p = (wi - wj) + s, d2 = px*px + py*py + pz*pz  -- no FMA contraction,
        // matches numpy reference association for exact mask agreement at d2==36 boundary
        float px = __fadd_rn(__fsub_rn(wix, wjx[dj]), sx);
        float py = __fadd_rn(__fsub_rn(wiy, wjy[dj]), sy);
        float pz = __fadd_rn(__fsub_rn(wiz, wjz[dj]), sz);
        float d2 = __fadd_rn(__fadd_rn(__fmul_rn(px, px), __fmul_rn(py, py)),
                             __fmul_rn(pz, pz));
        bool mb = (d2 < CUT2) && !((k == (K / 2)) && (i == j0 + dj));
        dist[dj] = mb ? sqrtf(d2) : 0.0f;
        msk[dj]  = mb ? 1.0f : 0.0f;
        pc[3 * dj + 0] = mb ? px : 0.0f;
        pc[3 * dj + 1] = mb ? py : 0.0f;
        pc[3 * dj + 2] = mb ? pz : 0.0f;
        int ox = imx - (oix - ojx[dj]) + 1;
        int oy = imy - (oiy - ojy[dj]) + 1;
        int oz = imz - (oiz - ojz[dj]) + 1;
        offv[dj] = (float)(oz + 3 * (oy + 3 * ox));
    }

    f32x4* out4 = reinterpret_cast<f32x4*>(out);
    f32x4 dv = { dist[0], dist[1], dist[2], dist[3] };
    f32x4 mv = { msk[0],  msk[1],  msk[2],  msk[3]  };
    f32x4 ov = { offv[0], offv[1], offv[2], offv[3] };
    f32x4 p0 = { pc[0], pc[1], pc[2],  pc[3]  };
    f32x4 p1 = { pc[4], pc[5], pc[6],  pc[7]  };
    f32x4 p2 = { pc[8], pc[9], pc[10], pc[11] };

    // dist/mask/offset: lane-contiguous, 1KB-aligned full-line NT stores
    __builtin_nontemporal_store(dv, out4 + t);
    __builtin_nontemporal_store(mv, out4 + 4 * F4 + t);
    __builtin_nontemporal_store(ov, out4 + 5 * F4 + t);

    // paircoord: LDS transpose so the global stores are lane-contiguous.
    // Block covers float4 range [F4 + 3*B0, F4 + 3*B0 + 768).
    lds[0][tid] = p0;
    lds[1][tid] = p1;
    lds[2][tid] = p2;
    __syncthreads();
    int base = F4 + 3 * (blockIdx.x * 256);
    #pragma unroll
    for (int rr = 0; rr < 3; ++rr) {
        int idx = rr * 256 + tid;         // 0..767, lane-consecutive
        int s = idx / 3;                  // source thread
        int q = idx - 3 * s;              // source piece
        __builtin_nontemporal_store(lds[q][s], out4 + base + idx);
    }
}

extern "C" void kernel_launch(void* const* d_in, const int* in_sizes, int n_in,
                              void* d_out, int out_size, void* d_ws, size_t ws_size,
                              hipStream_t stream) {
    const float* coords = (const float*)d_in[0];   // [M,N,3]
    const float* cell   = (const float*)d_in[1];   // [M,3,3]
    float* out = (float*)d_out;

    char* ws = (char*)d_ws;
    float* wrapped = (float*)(ws + WS_WRAPPED);
    int*   wo      = (int*)  (ws + WS_WO);
    float* shift   = (float*)(ws + WS_SHIFT);

    setup_kernel<<<M, 128, 0, stream>>>(coords, cell, wrapped, wo, shift);

    int total = M * K * N * (N / 4);           // 8,640,000 threads
    int blocks = total / 256;                  // 33,750 exactly
    pairs_kernel<<<blocks, 256, 0, stream>>>(wrapped, wo, shift, out);
}